// Round 14
// baseline (137.090 us; speedup 1.0000x reference)
//
#include <hip/hip_runtime.h>
#include <stdint.h>

#define UNITS 4096
#define WPB   4        // waves per block; each wave owns one full row
#define CAP   320      // per-row window count 242 +- 15.1 -> CAP = +5.2 sigma
#define NSLOT 5        // CAP/64
#define LOF   0.44f    // theta ~= 0.5244 +- 0.0206 ; [LO,HI) = +-4 sigma
#define HIF   0.61f
#define SELBITS 22     // bits(0.61f)-bits(0.44f) = 0x3AE148 < 2^22

typedef float v4f __attribute__((ext_vector_type(4)));

__device__ __forceinline__ uint32_t flipu(uint32_t b) {
    return b ^ (uint32_t)(((int32_t)b >> 31) | (int32_t)0x80000000);
}
__device__ __forceinline__ uint32_t mbcnt64(uint64_t m) {
    return __builtin_amdgcn_mbcnt_hi((uint32_t)(m >> 32),
           __builtin_amdgcn_mbcnt_lo((uint32_t)m, 0u));
}
// non-temporal 16B store (write-once output: don't pollute L2/L3)
__device__ __forceinline__ void nt_store4(float* p, float a, float b, float c, float d) {
    v4f v = {a, b, c, d};
    __builtin_nontemporal_store(v, (v4f*)p);
}

// One WAVE per row; 4 rows per 256-thread block. NO barriers, NO atomics,
// NO cross-wave communication anywhere.
// Pass 1: stream row (64 elem/lane), fused count-below-LO + window scatter
//         into the wave's PRIVATE LDS segment (ballot-ranked, in-order).
// Wave-local s_waitcnt lgkmcnt(0) orders scatter->gather (same wave's DS queue).
// Select: 2-bit/round MSB ballot radix over rebased 22-bit keys, once per row.
// Pass 2: re-read row (L2-hot: 16 KB/row, ~1 MB active per CU) + nt mask-store.
// Bracket+CAP verified per row; misses take the exact wave-local 32-bit
// bit-search fallback (re-reads row per round; ~0 rows expected).
__global__ __launch_bounds__(256, 8) void ksparse_select_kernel(
        const float* __restrict__ X, float* __restrict__ out, int kidx, int nrows) {
    __shared__ uint32_t list[WPB][CAP];   // 5 KiB, one private segment per wave

    const int t    = threadIdx.x;
    const int w    = t >> 6;
    const int lane = t & 63;

    const int row = (int)blockIdx.x * WPB + w;
    if (row >= nrows) return;             // wave-uniform; safe (no barriers)

    const float4* Xv = reinterpret_cast<const float4*>(X + (size_t)row * UNITS);
    float*        Ob = out + (size_t)row * UNITS;
    uint32_t*     seg = list[w];

    const uint32_t k   = (uint32_t)kidx;
    const uint32_t LOu = __float_as_uint(LOF);

    // ---- pass 1: fused count + private-segment scatter (no sync needed)
    uint32_t nb = 0, pfx = 0;
#pragma unroll
    for (int j = 0; j < 16; ++j) {
        const float4 v = Xv[j * 64 + lane];
        const float ff[4] = {v.x, v.y, v.z, v.w};
#pragma unroll
        for (int c = 0; c < 4; ++c) {
            const bool lo = ff[c] < LOF;
            const bool hi = ff[c] < HIF;
            const uint64_t mlo  = __ballot(lo);
            const uint64_t mwin = __ballot(hi && !lo);
            nb += (uint32_t)__popcll(mlo);
            if (hi && !lo) {
                const uint32_t off = pfx + mbcnt64(mwin);
                if (off < CAP) seg[off] = __float_as_uint(ff[c]) - LOu;
            }
            pfx += (uint32_t)__popcll(mwin);
        }
    }
    const uint32_t c  = pfx;   // window count (wave-uniform)
    const uint32_t cb = nb;    // count below LO (wave-uniform)

    // order the wave's own DS scatter before its DS gather (no s_barrier!)
    asm volatile("s_waitcnt lgkmcnt(0)" ::: "memory");
    __builtin_amdgcn_sched_barrier(0);

    if (cb <= k && k < cb + c && c <= CAP) {   // wave-uniform bracket check
        const uint32_t r = k - cb;             // rank of theta within the window

        uint32_t sv[NSLOT];
#pragma unroll
        for (int i = 0; i < NSLOT; ++i) {
            const uint32_t ix = (uint32_t)lane + 64u * i;
            sv[i] = (ix < c) ? seg[ix] : 0xFFFFFFFFu;
        }

        // MSB-first ballot radix select, 2 bits per round (11 rounds)
        uint32_t p = 0;
#pragma unroll
        for (int rb = SELBITS - 2; rb >= 0; rb -= 2) {
            const uint32_t m1 = p | (1u << rb);
            const uint32_t m2 = p | (2u << rb);
            const uint32_t m3 = p | (3u << rb);
            uint32_t n1 = 0, n2 = 0, n3 = 0;
#pragma unroll
            for (int i = 0; i < NSLOT; ++i) {
                n1 += (uint32_t)__popcll(__ballot(sv[i] < m1));
                n2 += (uint32_t)__popcll(__ballot(sv[i] < m2));
                n3 += (uint32_t)__popcll(__ballot(sv[i] < m3));
            }
            if (n3 <= r)      p = m3;   // wave-uniform
            else if (n2 <= r) p = m2;
            else if (n1 <= r) p = m1;
        }
        const float th = __uint_as_float(LOu + p);  // exact bits of theta

        // ---- pass 2: L2-hot re-read + nt mask-store
#pragma unroll
        for (int j = 0; j < 16; ++j) {
            const float4 v = Xv[j * 64 + lane];
            nt_store4(Ob + 4 * (j * 64 + lane),
                      (v.x >= th) ? v.x : 0.0f,
                      (v.y >= th) ? v.y : 0.0f,
                      (v.z >= th) ? v.z : 0.0f,
                      (v.w >= th) ? v.w : 0.0f);
        }
    } else {
        // exact wave-local fallback (~0 rows): 32-round MSB bit-search in
        // flipped space, re-reading the row (L2-hot) each round.
        uint32_t p = 0;
#pragma unroll 1
        for (int b = 31; b >= 0; --b) {
            const uint32_t mid = p | (1u << b);
            uint32_t cm = 0;
#pragma unroll 1
            for (int j = 0; j < 16; ++j) {
                const float4 v = Xv[j * 64 + lane];
                cm += (uint32_t)__popcll(__ballot(flipu(__float_as_uint(v.x)) < mid));
                cm += (uint32_t)__popcll(__ballot(flipu(__float_as_uint(v.y)) < mid));
                cm += (uint32_t)__popcll(__ballot(flipu(__float_as_uint(v.z)) < mid));
                cm += (uint32_t)__popcll(__ballot(flipu(__float_as_uint(v.w)) < mid));
            }
            if (cm <= k) p = mid;   // wave-uniform
        }
#pragma unroll 1
        for (int j = 0; j < 16; ++j) {
            const float4 v = Xv[j * 64 + lane];
            nt_store4(Ob + 4 * (j * 64 + lane),
                      (flipu(__float_as_uint(v.x)) >= p) ? v.x : 0.0f,
                      (flipu(__float_as_uint(v.y)) >= p) ? v.y : 0.0f,
                      (flipu(__float_as_uint(v.z)) >= p) ? v.z : 0.0f,
                      (flipu(__float_as_uint(v.w)) >= p) ? v.w : 0.0f);
        }
    }
}

extern "C" void kernel_launch(void* const* d_in, const int* in_sizes, int n_in,
                              void* d_out, int out_size, void* d_ws, size_t ws_size,
                              hipStream_t stream) {
    const float* X = (const float*)d_in[0];
    float* out = (float*)d_out;
    const int rows = in_sizes[0] / UNITS;
    const int kidx = (int)(0.7 * UNITS);  // 2867
    const int grid = (rows + WPB - 1) / WPB;
    ksparse_select_kernel<<<grid, 256, 0, stream>>>(X, out, kidx, rows);
}

// Round 15
// 93.628 us; speedup vs baseline: 1.4642x; 1.4642x over previous
//
#include <hip/hip_runtime.h>
#include <stdint.h>

#define UNITS  4096
#define SEG    64         // per-wave list segment; per-wave window count 44.1 +- 6.5 -> +3.1 sigma
#define CAP    (4 * SEG)  // 256
#define NSLOT  4          // CAP/64; slot i = wave-segment i, offset = lane
#define LOF    0.4625f    // theta ~= 0.5243 +- 0.0206 ; [LO,HI) ~= +-3 sigma
#define HIF    0.5865f
#define SELBITS 22        // bits(0.5865f)-bits(0.4625f) = 0x295911 < 2^22

typedef float v4f __attribute__((ext_vector_type(4)));

// LDS-only barrier (no vmcnt drain)
__device__ __forceinline__ void lds_barrier() {
    asm volatile("s_waitcnt lgkmcnt(0)" ::: "memory");
    __builtin_amdgcn_s_barrier();
}
__device__ __forceinline__ uint32_t flipu(uint32_t b) {
    return b ^ (uint32_t)(((int32_t)b >> 31) | (int32_t)0x80000000);
}
__device__ __forceinline__ uint32_t mbcnt64(uint64_t m) {
    return __builtin_amdgcn_mbcnt_hi((uint32_t)(m >> 32),
           __builtin_amdgcn_mbcnt_lo((uint32_t)m, 0u));
}
// non-temporal 16B store (write-once output: don't pollute L2/L3)
__device__ __forceinline__ void nt_store4(float* p, float a, float b, float c, float d) {
    v4f v = {a, b, c, d};
    __builtin_nontemporal_store(v, (v4f*)p);
}

// One block (256 threads) per row (R12 structure).
// Fused window ballots + per-wave-segment scatter (no atomics), ONE barrier,
// 4-wave redundant ballot bisection with COUNT-CONVERGED EARLY EXIT over
// rebased 22-bit keys, nt mask-store from registers. Bracket + per-wave
// segment overflow verified per row; misses take the exact 32-bit fallback.
__global__ __launch_bounds__(256, 8) void ksparse_select_kernel(
        const float* __restrict__ X, float* __restrict__ out, int kidx) {
    __shared__ uint32_t list[CAP];  // 1 KiB, per-wave segments of 64
    __shared__ uint32_t wnb[4];     // per-wave count below LO
    __shared__ uint32_t wc[4];      // per-wave window count (may exceed SEG)
    __shared__ uint32_t fbc[4];     // fallback per-wave counts

    const int t    = threadIdx.x;
    const int w    = t >> 6;
    const int lane = t & 63;

    // load row (coalesced float4)
    float f[16];
    {
        const float4* Xv = reinterpret_cast<const float4*>(X + (size_t)blockIdx.x * UNITS);
#pragma unroll
        for (int j = 0; j < 4; ++j) {
            float4 v = Xv[j * 256 + t];
            f[4*j] = v.x; f[4*j+1] = v.y; f[4*j+2] = v.z; f[4*j+3] = v.w;
        }
    }

    // fused window-count + segment scatter (single pass, no atomics)
    const uint32_t LOu = __float_as_uint(LOF);
    uint32_t nbw = 0, pfx = 0;
#pragma unroll
    for (int e = 0; e < 16; ++e) {
        const bool lo = f[e] < LOF;
        const bool hi = f[e] < HIF;
        const uint64_t mlo  = __ballot(lo);
        const uint64_t mwin = __ballot(hi && !lo);
        nbw += (uint32_t)__popcll(mlo);
        if (hi && !lo) {
            const uint32_t off = pfx + mbcnt64(mwin);
            if (off < SEG) list[SEG * w + off] = __float_as_uint(f[e]) - LOu;
        }
        pfx += (uint32_t)__popcll(mwin);
    }
    if (lane == 0) { wnb[w] = nbw; wc[w] = pfx; }

    lds_barrier();  // list + wnb + wc visible (the ONLY fast-path barrier)

    const uint32_t c0 = wc[0], c1 = wc[1], c2 = wc[2], c3 = wc[3];
    const uint32_t c  = c0 + c1 + c2 + c3;
    const uint32_t cb = wnb[0] + wnb[1] + wnb[2] + wnb[3];
    const uint32_t k  = (uint32_t)kidx;
    const uint32_t mx = max(max(c0, c1), max(c2, c3));

    float* Ob = out + (size_t)blockIdx.x * UNITS;

    if (cb <= k && k < cb + c && mx <= SEG) {   // block-uniform bracket check
        const uint32_t r = k - cb;              // rank of theta within the window

        // trivial distributed list load: slot i = segment i, offset = lane
        uint32_t sv[NSLOT];
        sv[0] = (lane < (int)c0) ? list[0 * SEG + lane] : 0xFFFFFFFFu;
        sv[1] = (lane < (int)c1) ? list[1 * SEG + lane] : 0xFFFFFFFFu;
        sv[2] = (lane < (int)c2) ? list[2 * SEG + lane] : 0xFFFFFFFFu;
        sv[3] = (lane < (int)c3) ? list[3 * SEG + lane] : 0xFFFFFFFFu;

        // MSB-first bisection, 2 bits/round, COUNT-CONVERGED EARLY EXIT.
        // Invariant: bl = #(keys < p) <= r < bh = #(keys < p+W); theta in [p,p+W).
        uint32_t p = 0, W = 1u << SELBITS, bl = 0, bh = c, thk = 0;
        while (true) {
            if (bh - bl == 1u) {   // unique candidate: extract it directly
                thk = p;           // (overwritten below; keeps compiler happy)
#pragma unroll
                for (int i = 0; i < NSLOT; ++i) {
                    const uint64_t m = __ballot((sv[i] - p) < W);   // wave-uniform count=0 or 1
                    if (m) {
                        const int ln = (int)(__ffsll((unsigned long long)m) - 1);
                        thk = __shfl(sv[i], ln);
                    }
                }
                break;
            }
            if (W <= 1u) { thk = p; break; }   // duplicate keys at rank: p is exact
            const uint32_t q  = W >> 2;
            const uint32_t m1 = p + q, m2 = p + 2 * q, m3 = p + 3 * q;
            uint32_t n1 = 0, n2 = 0, n3 = 0;
#pragma unroll
            for (int i = 0; i < NSLOT; ++i) {
                n1 += (uint32_t)__popcll(__ballot(sv[i] < m1));
                n2 += (uint32_t)__popcll(__ballot(sv[i] < m2));
                n3 += (uint32_t)__popcll(__ballot(sv[i] < m3));
            }
            if (n3 <= r)      { p = m3; bl = n3;          }
            else if (n2 <= r) { p = m2; bl = n2; bh = n3; }
            else if (n1 <= r) { p = m1; bl = n1; bh = n2; }
            else              {                  bh = n1; }
            W = q;
        }
        const float th = __uint_as_float(LOu + thk);  // exact bits of theta

#pragma unroll
        for (int j = 0; j < 4; ++j) {
            nt_store4(Ob + 4 * (j * 256 + t),
                      (f[4*j]   >= th) ? f[4*j]   : 0.0f,
                      (f[4*j+1] >= th) ? f[4*j+1] : 0.0f,
                      (f[4*j+2] >= th) ? f[4*j+2] : 0.0f,
                      (f[4*j+3] >= th) ? f[4*j+3] : 0.0f);
        }
    } else {
        // exact block-wide fallback (~100 rows/dataset at +-3 sigma window):
        // 32-bit MSB bit-search in flipped space
        uint32_t p = 0;
#pragma unroll 1
        for (int b = 31; b >= 0; --b) {
            const uint32_t mid = p | (1u << b);
            uint32_t cw = 0;
#pragma unroll
            for (int e = 0; e < 16; ++e)
                cw += (uint32_t)__popcll(__ballot(flipu(__float_as_uint(f[e])) < mid));
            if (lane == 0) fbc[w] = cw;
            lds_barrier();
            const uint32_t cm = fbc[0] + fbc[1] + fbc[2] + fbc[3];
            if (cm <= k) p = mid;   // block-uniform
            lds_barrier();          // fbc consumed before next overwrite
        }
#pragma unroll
        for (int j = 0; j < 4; ++j) {
            nt_store4(Ob + 4 * (j * 256 + t),
                      (flipu(__float_as_uint(f[4*j]))   >= p) ? f[4*j]   : 0.0f,
                      (flipu(__float_as_uint(f[4*j+1])) >= p) ? f[4*j+1] : 0.0f,
                      (flipu(__float_as_uint(f[4*j+2])) >= p) ? f[4*j+2] : 0.0f,
                      (flipu(__float_as_uint(f[4*j+3])) >= p) ? f[4*j+3] : 0.0f);
        }
    }
}

extern "C" void kernel_launch(void* const* d_in, const int* in_sizes, int n_in,
                              void* d_out, int out_size, void* d_ws, size_t ws_size,
                              hipStream_t stream) {
    const float* X = (const float*)d_in[0];
    float* out = (float*)d_out;
    const int rows = in_sizes[0] / UNITS;
    const int kidx = (int)(0.7 * UNITS);  // 2867
    ksparse_select_kernel<<<rows, 256, 0, stream>>>(X, out, kidx);
}